// Round 3
// baseline (674.509 us; speedup 1.0000x reference)
//
#include <hip/hip_runtime.h>

typedef __attribute__((ext_vector_type(8))) short short8;
typedef __attribute__((ext_vector_type(4))) float floatx4;

#define MFMA16(a,b,c) __builtin_amdgcn_mfma_f32_16x16x32_bf16(a,b,c,0,0,0)

__device__ __forceinline__ unsigned short f2bf(float f){
  unsigned u = __float_as_uint(f);
  u += 0x7fffu + ((u >> 16) & 1u);
  return (unsigned short)(u >> 16);
}
__device__ __forceinline__ float sigm(float x){ return 1.f/(1.f+__expf(-x)); }

// ---- fused prep: init + WgT transpose + cwT transpose + adjacency bitmasks ----
__global__ __launch_bounds__(256) void prep_kernel(const float* __restrict__ actors,
    const float* __restrict__ h0, const float* __restrict__ Wg, const float* __restrict__ cw,
    const int* __restrict__ adj, unsigned short* __restrict__ hbf, float* __restrict__ cell,
    unsigned short* __restrict__ WgT, float* __restrict__ cwT, unsigned long long* __restrict__ bm){
  int bid = blockIdx.x;
  if (bid < 1024){
    int idx = bid*256 + threadIdx.x;
    int n = idx >> 7, c = idx & 127;
    hbf[idx]  = f2bf(h0[c]);
    cell[idx] = actors[(size_t)n*2560 + c];
  } else if (bid < 1536){
    int e = (bid-1024)*256 + threadIdx.x;            // 131072
    int g = e >> 15, o = (e >> 8) & 127, f = e & 255;
    WgT[(size_t)g*32768 + o*256 + f] = f2bf(Wg[(size_t)g*32768 + f*128 + o]);
  } else if (bid < 1728){
    int e = (bid-1536)*256 + threadIdx.x;            // 49152
    int l = e >> 14, rr = e & 16383, k = rr >> 7, o = rr & 127;
    cwT[(size_t)l*32768 + k*256 + o]       = cw[(size_t)l*32768 + o*256 + k*2];
    cwT[(size_t)l*32768 + k*256 + 128 + o] = cw[(size_t)l*32768 + o*256 + k*2 + 1];
  } else {
    const int E[4] = {0,4,9,14};
    int mb = bid - 1728;                             // 2048 blocks
    int t = mb & 3, nblk = mb >> 2;
    int wv = threadIdx.x >> 6, lane = threadIdx.x & 63;
    int n = nblk*4 + wv;
    const int* row = adj + (size_t)n*40960 + (size_t)E[t]*2048;
    unsigned long long* outp = bm + ((size_t)t*2048 + n)*32;
    for (int it=0; it<32; ++it){
      unsigned long long bal = __ballot(row[it*64 + lane] > 0);
      if (lane == 0) outp[it] = bal;
    }
  }
}

// ---- WhT[g][o][n] bf16 = (Wg^T @ [X|h]^T), MFMA K=256; s_src/s_dst from fp32 acc ----
__global__ __launch_bounds__(256) void whgemm_kernel(const float* __restrict__ actors,
    const unsigned short* __restrict__ hbf, const unsigned short* __restrict__ WgT,
    const float* __restrict__ ag, unsigned short* __restrict__ WhT,
    float* __restrict__ s_src, float* __restrict__ s_dst, int xoff){
  __shared__ __align__(16) unsigned short ginb[32*264];   // [n=32][k=256 +8 pad]
  __shared__ float sred[4][2][32];
  int g = blockIdx.y, n0 = blockIdx.x*32, tid = threadIdx.x;
  { // stage gin tile as bf16
    int row = tid >> 3, q = tid & 7;
    if (q < 4){
      const float4* src = (const float4*)(actors + (size_t)(n0+row)*2560 + xoff + q*32);
      unsigned short* dst = &ginb[row*264 + q*32];
      #pragma unroll
      for (int j=0;j<4;++j){
        float4 a = src[2*j], b = src[2*j+1];
        unsigned short tmp[8] = {f2bf(a.x),f2bf(a.y),f2bf(a.z),f2bf(a.w),
                                 f2bf(b.x),f2bf(b.y),f2bf(b.z),f2bf(b.w)};
        *(uint4*)(dst + j*8) = *(const uint4*)tmp;
      }
    } else {
      const uint4* src = (const uint4*)(hbf + (size_t)(n0+row)*128 + (q-4)*32);
      uint4* dst = (uint4*)&ginb[row*264 + 128 + (q-4)*32];
      #pragma unroll
      for (int j=0;j<4;++j) dst[j] = src[j];
    }
  }
  __syncthreads();
  int wv = tid>>6, lane = tid&63, quad = lane>>4, l16 = lane&15;
  int ob = wv*32;
  floatx4 acc[2][2];
  #pragma unroll
  for (int i=0;i<2;++i) for (int j=0;j<2;++j) acc[i][j] = (floatx4){0.f,0.f,0.f,0.f};
  const unsigned short* wga = WgT + (size_t)g*32768;
  #pragma unroll
  for (int kh=0; kh<8; ++kh){
    int k = kh*32 + quad*8;
    short8 a0 = *(const short8*)(wga + (size_t)(ob + l16)*256 + k);
    short8 a1 = *(const short8*)(wga + (size_t)(ob + 16 + l16)*256 + k);
    #pragma unroll
    for (int j=0;j<2;++j){
      short8 b = *(const short8*)&ginb[(j*16 + l16)*264 + k];
      acc[0][j] = MFMA16(a0, b, acc[0][j]);
      acc[1][j] = MFMA16(a1, b, acc[1][j]);
    }
  }
  float agS[2][4], agD[2][4];
  #pragma unroll
  for (int i=0;i<2;++i)
    #pragma unroll
    for (int r=0;r<4;++r){
      int o = ob + i*16 + quad*4 + r;
      agS[i][r] = ag[g*256 + o];
      agD[i][r] = ag[g*256 + 128 + o];
    }
  unsigned short* wht = WhT + (size_t)g*262144;
  float psrc[2], pdst[2];
  #pragma unroll
  for (int j=0;j<2;++j){
    float ps = 0.f, pd = 0.f;
    #pragma unroll
    for (int i=0;i<2;++i)
      #pragma unroll
      for (int r=0;r<4;++r){
        float v = acc[i][j][r];
        ps += v*agS[i][r]; pd += v*agD[i][r];
        wht[(size_t)(ob + i*16 + quad*4 + r)*2048 + n0 + j*16 + l16] = f2bf(v);
      }
    psrc[j] = ps; pdst[j] = pd;
  }
  #pragma unroll
  for (int j=0;j<2;++j){
    psrc[j] += __shfl_down(psrc[j], 16); psrc[j] += __shfl_down(psrc[j], 32);
    pdst[j] += __shfl_down(pdst[j], 16); pdst[j] += __shfl_down(pdst[j], 32);
  }
  if (quad == 0){
    #pragma unroll
    for (int j=0;j<2;++j){
      sred[wv][0][j*16+l16] = psrc[j];
      sred[wv][1][j*16+l16] = pdst[j];
    }
  }
  __syncthreads();
  if (tid < 64){
    int which = tid>>5, n = tid&31;
    float s = sred[0][which][n]+sred[1][which][n]+sred[2][which][n]+sred[3][which][n];
    (which ? s_dst : s_src)[g*2048 + n0 + n] = s;
  }
}

// ---- barrier-free fused masked-softmax + PV ----
// 512 thr = 8 waves = (4 m-groups) x (2 o-halves); 16-row n-tile; A-frag generated
// in-register in MFMA A layout; B-frag short8 straight from L2-resident WhT.
__global__ __launch_bounds__(512) void attn_kernel(const unsigned char* __restrict__ bmb,
    const unsigned short* __restrict__ WhT, const float* __restrict__ s_src,
    const float* __restrict__ s_dst, float* __restrict__ gout, int t){
  __shared__ float obuf[2][2][16][72];   // [ohalf][region][row][o +pad] = 18 KB
  __shared__ float zpart[4][16];
  __shared__ float zrow[16];
  int g = blockIdx.y, n0 = blockIdx.x*16, tid = threadIdx.x;
  int w = tid>>6, lane = tid&63, quad = lane>>4, l16 = lane&15;
  int ohalf = w & 1, mg = w >> 1;
  const unsigned short* whg = WhT + (size_t)g*262144 + (size_t)(ohalf*64)*2048;
  const float* sd = s_dst + g*2048;
  float srcv = s_src[g*2048 + n0 + l16];
  const unsigned char* mr = bmb + ((size_t)t*2048 + n0 + l16)*256;
  float z0 = 0.f;
  floatx4 acc[4];
  #pragma unroll
  for (int j=0;j<4;++j) acc[j] = (floatx4){0.f,0.f,0.f,0.f};
  for (int c=0;c<8;++c){
    int mbase = mg*512 + c*64;
    #pragma unroll
    for (int kh=0; kh<2; ++kh){
      int mk = mbase + kh*32 + quad*8;
      float4 sda = *(const float4*)(sd + mk);
      float4 sdb = *(const float4*)(sd + mk + 4);
      unsigned mb = mr[mk>>3];
      float sv[8] = {sda.x,sda.y,sda.z,sda.w,sdb.x,sdb.y,sdb.z,sdb.w};
      short8 a0;
      #pragma unroll
      for (int j=0;j<8;++j){
        float s = srcv + sv[j];
        s = s > 0.f ? s : 0.2f*s;                 // leaky_relu
        float p = ((mb >> j) & 1u) ? __expf(s) : 0.f;
        z0 += p;
        a0[j] = (short)f2bf(p);
      }
      const unsigned short* bp = whg + mk;
      #pragma unroll
      for (int j=0;j<4;++j){
        short8 b = *(const short8*)(bp + (size_t)(j*16 + l16)*2048);
        acc[j] = MFMA16(a0, b, acc[j]);
      }
    }
  }
  // z: fold quads, stash per-m-group partial (even waves only; odd waves are dup exp)
  z0 += __shfl_down(z0, 32);
  z0 += __shfl_down(z0, 16);
  if (ohalf == 0 && lane < 16) zpart[mg][l16] = z0;
  // O: cross-wave reduce via LDS (2 regions per o-half)
  if (mg < 2){
    #pragma unroll
    for (int j=0;j<4;++j)
      #pragma unroll
      for (int r=0;r<4;++r)
        obuf[ohalf][mg][quad*4+r][j*16+l16] = acc[j][r];
  }
  __syncthreads();
  if (mg >= 2){
    #pragma unroll
    for (int j=0;j<4;++j)
      #pragma unroll
      for (int r=0;r<4;++r)
        obuf[ohalf][mg-2][quad*4+r][j*16+l16] += acc[j][r];
  }
  if (tid < 16) zrow[tid] = zpart[0][tid]+zpart[1][tid]+zpart[2][tid]+zpart[3][tid];
  __syncthreads();
  { // normalize + elu + store: 4 floats/thread
    int row = tid>>5, c0 = (tid&31)*4;
    int half = c0>>6, oc = c0&63;
    float inv = 1.f / zrow[row];
    float* go = gout + (size_t)g*262144 + (size_t)(n0+row)*128 + c0;
    #pragma unroll
    for (int j=0;j<4;++j){
      float v = (obuf[half][0][row][oc+j] + obuf[half][1][row][oc+j]) * inv;
      go[j] = v > 0.f ? v : __expf(v) - 1.f;     // elu
    }
  }
}

// ---- LSTM gate combine + hidden@W out-projection ----
__global__ __launch_bounds__(256) void gate_kernel(const float* __restrict__ gbuf,
    float* __restrict__ cell, unsigned short* __restrict__ hbf, const float* __restrict__ W,
    const float* __restrict__ b, float* __restrict__ y, int t){
  __shared__ float h[256];
  int tid = threadIdx.x;
  int r = tid >> 7, o = tid & 127;
  int n = blockIdx.x*2 + r;
  size_t idx = (size_t)n*128 + o;
  float g0 = gbuf[idx], g1 = gbuf[262144+idx], g2 = gbuf[524288+idx], g3 = gbuf[786432+idx];
  float fg = sigm(g0), ig = sigm(g1), ic = tanhf(g2), og = sigm(g3);
  float cl = cell[idx]*fg + ig*ic;
  float hd = tanhf(cl)*og;
  cell[idx] = cl; hbf[idx] = f2bf(hd);
  h[tid] = hd;
  __syncthreads();
  float acc = b[o];
  const float* hr = h + r*128;
  for (int k=0;k<128;++k) acc += hr[k]*W[k*128+o];
  y[(size_t)n*512 + o*4 + t] = sigm(acc);
}

// ---- all 3 temporal conv layers fused (row-independent) ----
__global__ __launch_bounds__(256) void convfused_kernel(const float* __restrict__ yin,
    const float* __restrict__ cwT, const float* __restrict__ cb, float* __restrict__ out){
  __shared__ float ylds[2][128][4];
  int tid = threadIdx.x;
  int r = tid >> 7, o = tid & 127;
  int n = blockIdx.x*2 + r;
  *(float4*)&ylds[r][o][0] = *(const float4*)&yin[(size_t)n*512 + o*4];
  __syncthreads();
  { // layer 0: 4 -> 3
    const float* w = cwT;
    float a0=0.f, a1=0.f, a2=0.f;
    for (int k=0;k<128;++k){
      float w0 = w[k*256 + o], w1 = w[k*256 + 128 + o];
      float y0 = ylds[r][k][0], y1 = ylds[r][k][1], y2 = ylds[r][k][2], y3 = ylds[r][k][3];
      a0 += y0*w0 + y1*w1; a1 += y1*w0 + y2*w1; a2 += y2*w0 + y3*w1;
    }
    float bb = cb[o];
    __syncthreads();
    ylds[r][o][0] = a0+bb; ylds[r][o][1] = a1+bb; ylds[r][o][2] = a2+bb;
    __syncthreads();
  }
  { // layer 1: 3 -> 2
    const float* w = cwT + 32768;
    float a0=0.f, a1=0.f;
    for (int k=0;k<128;++k){
      float w0 = w[k*256 + o], w1 = w[k*256 + 128 + o];
      float y0 = ylds[r][k][0], y1 = ylds[r][k][1], y2 = ylds[r][k][2];
      a0 += y0*w0 + y1*w1; a1 += y1*w0 + y2*w1;
    }
    float bb = cb[128 + o];
    __syncthreads();
    ylds[r][o][0] = a0+bb; ylds[r][o][1] = a1+bb;
    __syncthreads();
  }
  { // layer 2: 2 -> 1, write final
    const float* w = cwT + 65536;
    float a0=0.f;
    for (int k=0;k<128;++k){
      float w0 = w[k*256 + o], w1 = w[k*256 + 128 + o];
      a0 += ylds[r][k][0]*w0 + ylds[r][k][1]*w1;
    }
    out[(size_t)n*128 + o] = a0 + cb[256 + o];
  }
}

extern "C" void kernel_launch(void* const* d_in, const int* in_sizes, int n_in,
                              void* d_out, int out_size, void* d_ws, size_t ws_size,
                              hipStream_t stream) {
  const float* actors = (const float*)d_in[0];
  const int*   adj    = (const int*)d_in[1];
  const float* Wg     = (const float*)d_in[2];
  const float* ag     = (const float*)d_in[3];
  const float* W      = (const float*)d_in[4];
  const float* b      = (const float*)d_in[5];
  const float* h0     = (const float*)d_in[6];
  const float* cw     = (const float*)d_in[7];
  const float* cb     = (const float*)d_in[8];
  float* out = (float*)d_out;

  char* ws = (char*)d_ws;
  unsigned long long* bm = (unsigned long long*)ws;                  // 2 MB
  float* cell          = (float*)(ws + (size_t)(2u<<20));            // 1 MB
  unsigned short* hbf  = (unsigned short*)(ws + (size_t)(3u<<20));   // 512 KB bf16 [n][k]
  unsigned short* WgT  = (unsigned short*)(ws + (size_t)3670016);    // 256 KB bf16 [g][o][f]
  float* s_src         = (float*)(ws + (size_t)3932160);             // 32 KB
  float* s_dst         = (float*)(ws + (size_t)3932160 + 32768);     // 32 KB
  unsigned short* WhT  = (unsigned short*)(ws + (size_t)(4u<<20));   // 2 MB bf16 [g][o][n]
  float* cwT           = (float*)(ws + (size_t)(6u<<20));            // 384 KB [l][k][tap][o]
  float* gbuf          = (float*)(ws + (size_t)(7u<<20));            // 4 MB [g][n][o]
  float* yA            = (float*)(ws + (size_t)(11u<<20));           // 4 MB [n][o][4]

  const int XI[4] = {4, 9, 14, 19};

  prep_kernel<<<3776, 256, 0, stream>>>(actors, h0, Wg, cw, adj, hbf, cell, WgT, cwT, bm);
  for (int t=0; t<4; ++t){
    whgemm_kernel<<<dim3(64,4), 256, 0, stream>>>(actors, hbf, WgT, ag, WhT, s_src, s_dst, XI[t]*128);
    attn_kernel  <<<dim3(128,4), 512, 0, stream>>>((const unsigned char*)bm, WhT, s_src, s_dst, gbuf, t);
    gate_kernel  <<<1024, 256, 0, stream>>>(gbuf, cell, hbf, W, b, yA, t);
  }
  convfused_kernel<<<1024, 256, 0, stream>>>(yA, cwT, cb, out);
}

// Round 4
// 622.207 us; speedup vs baseline: 1.0841x; 1.0841x over previous
//
#include <hip/hip_runtime.h>

typedef __attribute__((ext_vector_type(8))) short short8;
typedef __attribute__((ext_vector_type(4))) float floatx4;

#define MFMA16(a,b,c) __builtin_amdgcn_mfma_f32_16x16x32_bf16(a,b,c,0,0,0)

__device__ __forceinline__ unsigned short f2bf(float f){
  unsigned u = __float_as_uint(f);
  u += 0x7fffu + ((u >> 16) & 1u);
  return (unsigned short)(u >> 16);
}
__device__ __forceinline__ float sigm(float x){ return 1.f/(1.f+__expf(-x)); }

// WhB/WgA swizzled B/A-fragment layouts:
//  element (o, m):  flat = (o>>4)*32768 + (m>>5)*512 + (((m>>3)&3)*16 + (o&15))*8 + (m&7)
//  -> a wave's 64 lanes (lane = quad*16+l16) read 1KB contiguous per (o16, m32) chunk.

// ---- fused prep: cell init + WgA swizzle + cwT transpose + adjacency bitmasks ----
__global__ __launch_bounds__(256) void prep_kernel(const float* __restrict__ actors,
    const float* __restrict__ Wg, const float* __restrict__ cw, const int* __restrict__ adj,
    float* __restrict__ cell, unsigned short* __restrict__ WgA, float* __restrict__ cwT,
    unsigned long long* __restrict__ bm){
  int bid = blockIdx.x;
  if (bid < 1024){
    int idx = bid*256 + threadIdx.x;
    int n = idx >> 7, c = idx & 127;
    cell[idx] = actors[(size_t)n*2560 + c];
  } else if (bid < 1536){
    int e = (bid-1024)*256 + threadIdx.x;            // 131072
    int g = e >> 15, o = (e >> 8) & 127, k = e & 255;
    unsigned short v = f2bf(Wg[(size_t)g*32768 + k*128 + o]);
    int off = ((o>>4)*8 + (k>>5))*512 + (((k>>3)&3)*16 + (o&15))*8 + (k&7);
    WgA[(size_t)g*32768 + off] = v;
  } else if (bid < 1728){
    int e = (bid-1536)*256 + threadIdx.x;            // 49152
    int l = e >> 14, rr = e & 16383, k = rr >> 7, o = rr & 127;
    cwT[(size_t)l*32768 + k*256 + o]       = cw[(size_t)l*32768 + o*256 + k*2];
    cwT[(size_t)l*32768 + k*256 + 128 + o] = cw[(size_t)l*32768 + o*256 + k*2 + 1];
  } else {
    const int E[4] = {0,4,9,14};
    int mb = bid - 1728;                             // 2048 blocks
    int t = mb & 3, nblk = mb >> 2;
    int wv = threadIdx.x >> 6, lane = threadIdx.x & 63;
    int n = nblk*4 + wv;
    const int* row = adj + (size_t)n*40960 + (size_t)E[t]*2048;
    unsigned long long* outp = bm + ((size_t)t*2048 + n)*32;
    for (int it=0; it<32; ++it){
      unsigned long long bal = __ballot(row[it*64 + lane] > 0);
      if (lane == 0) outp[it] = bal;
    }
  }
}

// ---- fused: LSTM gate (from gbuf_{t-1}) + y-plane outproj + 4-gate Wh GEMM ----
// grid 128 x 256 threads; 16 rows per block.
__global__ __launch_bounds__(256) void gatewh_kernel(const float* __restrict__ actors,
    const float* __restrict__ gbuf, float* __restrict__ cell, const float* __restrict__ h0,
    const float* __restrict__ W, const float* __restrict__ bvec,
    const unsigned short* __restrict__ WgA, const float* __restrict__ ag,
    float* __restrict__ y, unsigned short* __restrict__ WhB,
    float* __restrict__ s_src, float* __restrict__ s_dst, int xoff, int t){
  __shared__ float hl[16][132];
  __shared__ __align__(16) unsigned short ginb[16*264];
  __shared__ float sredS[4][4][16], sredD[4][4][16];
  int n0 = blockIdx.x*16, tid = threadIdx.x;
  int row = tid>>4, o0 = (tid&15)*8;
  // Phase A: hidden (+cell, from previous gates)
  if (t == 0){
    const float* hp = h0 + o0;
    #pragma unroll
    for (int j=0;j<8;++j) hl[row][o0+j] = hp[j];
  } else {
    size_t idx = (size_t)(n0+row)*128 + o0;
    float4 ga0 = *(const float4*)(gbuf+idx),          ga1 = *(const float4*)(gbuf+idx+4);
    float4 gb0 = *(const float4*)(gbuf+262144+idx),   gb1 = *(const float4*)(gbuf+262144+idx+4);
    float4 gc0 = *(const float4*)(gbuf+524288+idx),   gc1 = *(const float4*)(gbuf+524288+idx+4);
    float4 gd0 = *(const float4*)(gbuf+786432+idx),   gd1 = *(const float4*)(gbuf+786432+idx+4);
    float4 c0 = *(const float4*)(cell+idx),           c1 = *(const float4*)(cell+idx+4);
    float fgv[8] = {ga0.x,ga0.y,ga0.z,ga0.w,ga1.x,ga1.y,ga1.z,ga1.w};
    float igv[8] = {gb0.x,gb0.y,gb0.z,gb0.w,gb1.x,gb1.y,gb1.z,gb1.w};
    float icv[8] = {gc0.x,gc0.y,gc0.z,gc0.w,gc1.x,gc1.y,gc1.z,gc1.w};
    float ogv[8] = {gd0.x,gd0.y,gd0.z,gd0.w,gd1.x,gd1.y,gd1.z,gd1.w};
    float cv[8]  = {c0.x,c0.y,c0.z,c0.w,c1.x,c1.y,c1.z,c1.w};
    float cl[8], hd[8];
    #pragma unroll
    for (int j=0;j<8;++j){
      cl[j] = cv[j]*sigm(fgv[j]) + sigm(igv[j])*tanhf(icv[j]);
      hd[j] = tanhf(cl[j])*sigm(ogv[j]);
      hl[row][o0+j] = hd[j];
    }
    *(float4*)(cell+idx)   = (float4){cl[0],cl[1],cl[2],cl[3]};
    *(float4*)(cell+idx+4) = (float4){cl[4],cl[5],cl[6],cl[7]};
  }
  __syncthreads();
  // outproj y plane t-1
  if (t >= 1){
    float acc[8];
    float4 b0 = *(const float4*)(bvec+o0), b1 = *(const float4*)(bvec+o0+4);
    acc[0]=b0.x;acc[1]=b0.y;acc[2]=b0.z;acc[3]=b0.w;acc[4]=b1.x;acc[5]=b1.y;acc[6]=b1.z;acc[7]=b1.w;
    for (int k=0;k<128;++k){
      float hv = hl[row][k];
      float4 w0 = *(const float4*)(W + (size_t)k*128 + o0);
      float4 w1 = *(const float4*)(W + (size_t)k*128 + o0 + 4);
      acc[0]+=hv*w0.x; acc[1]+=hv*w0.y; acc[2]+=hv*w0.z; acc[3]+=hv*w0.w;
      acc[4]+=hv*w1.x; acc[5]+=hv*w1.y; acc[6]+=hv*w1.z; acc[7]+=hv*w1.w;
    }
    float* yp = y + (size_t)(t-1)*262144 + (size_t)(n0+row)*128 + o0;
    #pragma unroll
    for (int j=0;j<8;++j) yp[j] = sigm(acc[j]);
  }
  // Phase B: gin bf16 = [X | hidden]
  {
    const float* ap = actors + (size_t)(n0+row)*2560 + xoff + o0;
    float4 a = *(const float4*)ap, bb = *(const float4*)(ap+4);
    unsigned short tmp[8] = {f2bf(a.x),f2bf(a.y),f2bf(a.z),f2bf(a.w),
                             f2bf(bb.x),f2bf(bb.y),f2bf(bb.z),f2bf(bb.w)};
    *(uint4*)&ginb[row*264 + o0] = *(const uint4*)tmp;
    unsigned short tmp2[8];
    #pragma unroll
    for (int j=0;j<8;++j) tmp2[j] = f2bf(hl[row][o0+j]);
    *(uint4*)&ginb[row*264 + 128 + o0] = *(const uint4*)tmp2;
  }
  __syncthreads();
  // Phase C: 4-gate GEMM, wave w -> o in [w*32, w*32+32)
  int w = tid>>6, lane = tid&63, quad = lane>>4, l16 = lane&15;
  int m32 = blockIdx.x>>1, min32 = (blockIdx.x&1)*16 + l16;
  int qp = min32>>3, jp = min32&7;
  for (int g=0; g<4; ++g){
    floatx4 acc0 = {0.f,0.f,0.f,0.f}, acc1 = acc0;
    const unsigned short* wa = WgA + (size_t)g*32768;
    #pragma unroll
    for (int kh=0; kh<8; ++kh){
      short8 bfr = *(const short8*)&ginb[l16*264 + kh*32 + quad*8];
      short8 a0 = *(const short8*)(wa + (size_t)(((w*2+0)*8 + kh)*64 + lane)*8);
      short8 a1 = *(const short8*)(wa + (size_t)(((w*2+1)*8 + kh)*64 + lane)*8);
      acc0 = MFMA16(a0, bfr, acc0);
      acc1 = MFMA16(a1, bfr, acc1);
    }
    float ps = 0.f, pd = 0.f;
    unsigned short* wb = WhB + (size_t)(g*8 + w*2)*32768 + m32*512 + qp*128 + jp;
    const float* agp = ag + g*256;
    #pragma unroll
    for (int i=0;i<2;++i){
      floatx4 ac = i ? acc1 : acc0;
      #pragma unroll
      for (int r=0;r<4;++r){
        int o = w*32 + i*16 + quad*4 + r;
        float v = ac[r];
        ps += v*agp[o]; pd += v*agp[128+o];
        wb[i*32768 + (quad*4+r)*8] = f2bf(v);
      }
    }
    ps += __shfl_down(ps,32); ps += __shfl_down(ps,16);
    pd += __shfl_down(pd,32); pd += __shfl_down(pd,16);
    if (lane < 16){ sredS[g][w][l16] = ps; sredD[g][w][l16] = pd; }
  }
  __syncthreads();
  if (tid < 128){
    int g = tid>>5, which = (tid>>4)&1, n = tid&15;
    float s;
    if (which) s = sredD[g][0][n]+sredD[g][1][n]+sredD[g][2][n]+sredD[g][3][n];
    else       s = sredS[g][0][n]+sredS[g][1][n]+sredS[g][2][n]+sredS[g][3][n];
    (which ? s_dst : s_src)[g*2048 + n0 + n] = s;
  }
}

// ---- fused masked-softmax + PV: 256 thr = 4 m-waves, full-o per wave ----
__global__ __launch_bounds__(256) void attn_kernel(const unsigned char* __restrict__ bmb,
    const unsigned short* __restrict__ WhB, const float* __restrict__ s_src,
    const float* __restrict__ s_dst, float* __restrict__ gout, int t){
  __shared__ float obuf[2][16][132];
  __shared__ float zpart[4][16];
  int g = blockIdx.y, n0 = blockIdx.x*16, tid = threadIdx.x;
  int w = tid>>6, lane = tid&63, quad = lane>>4, l16 = lane&15;
  float srcv = s_src[g*2048 + n0 + l16];
  const float* sd = s_dst + g*2048;
  // preload lane's 64-byte mask strip (row n0+l16, m in [w*512, w*512+512))
  const unsigned char* mrow = bmb + ((size_t)t*2048 + n0 + l16)*256 + w*64;
  uint4 mq0 = *(const uint4*)mrow,      mq1 = *(const uint4*)(mrow+16);
  uint4 mq2 = *(const uint4*)(mrow+32), mq3 = *(const uint4*)(mrow+48);
  unsigned mwd[16] = {mq0.x,mq0.y,mq0.z,mq0.w, mq1.x,mq1.y,mq1.z,mq1.w,
                      mq2.x,mq2.y,mq2.z,mq2.w, mq3.x,mq3.y,mq3.z,mq3.w};
  const unsigned short* wb = WhB + (size_t)g*262144;
  float z0 = 0.f;
  floatx4 acc[8];
  #pragma unroll
  for (int j=0;j<8;++j) acc[j] = (floatx4){0.f,0.f,0.f,0.f};
  #pragma unroll
  for (int c=0; c<16; ++c){
    int mk = w*512 + c*32 + quad*8;
    float4 sa = *(const float4*)(sd + mk);
    float4 sb = *(const float4*)(sd + mk + 4);
    unsigned mb = (mwd[c] >> (quad*8)) & 0xffu;
    float sv[8] = {sa.x,sa.y,sa.z,sa.w,sb.x,sb.y,sb.z,sb.w};
    short8 a0;
    #pragma unroll
    for (int j=0;j<8;++j){
      float s = srcv + sv[j];
      s = s > 0.f ? s : 0.2f*s;                    // leaky_relu
      float p = ((mb >> j) & 1u) ? __expf(s) : 0.f;
      z0 += p;
      a0[j] = (short)f2bf(p);
    }
    const unsigned short* bp = wb + (size_t)(w*16 + c)*512 + lane*8;
    #pragma unroll
    for (int o16=0; o16<8; ++o16){
      short8 bfr = *(const short8*)(bp + (size_t)o16*32768);
      acc[o16] = MFMA16(a0, bfr, acc[o16]);
    }
  }
  z0 += __shfl_down(z0,32); z0 += __shfl_down(z0,16);
  if (lane < 16) zpart[w][l16] = z0;
  if (w < 2){
    #pragma unroll
    for (int o16=0;o16<8;++o16)
      #pragma unroll
      for (int r=0;r<4;++r)
        obuf[w][quad*4+r][o16*16+l16] = acc[o16][r];
  }
  __syncthreads();
  if (w >= 2){
    #pragma unroll
    for (int o16=0;o16<8;++o16)
      #pragma unroll
      for (int r=0;r<4;++r)
        obuf[w-2][quad*4+r][o16*16+l16] += acc[o16][r];
  }
  __syncthreads();
  { // normalize + elu + store
    int row = tid>>4, c0 = (tid&15)*8;
    float z = zpart[0][row]+zpart[1][row]+zpart[2][row]+zpart[3][row];
    float inv = 1.f / z;
    float* go = gout + (size_t)g*262144 + (size_t)(n0+row)*128 + c0;
    #pragma unroll
    for (int j=0;j<8;++j){
      float v = (obuf[0][row][c0+j] + obuf[1][row][c0+j]) * inv;
      go[j] = v > 0.f ? v : __expf(v) - 1.f;       // elu
    }
  }
}

// ---- final gate + y3 + all 3 temporal conv layers ----
__global__ __launch_bounds__(256) void convgate_kernel(const float* __restrict__ gbuf,
    const float* __restrict__ cell, const float* __restrict__ W, const float* __restrict__ bvec,
    const float* __restrict__ y, const float* __restrict__ cwT, const float* __restrict__ cb,
    float* __restrict__ out){
  __shared__ float hl[2][128];
  __shared__ float ylds[2][128][4];
  int tid = threadIdx.x;
  int r = tid >> 7, o = tid & 127;
  int n = blockIdx.x*2 + r;
  size_t idx = (size_t)n*128 + o;
  { // gate_3
    float g0 = gbuf[idx], g1 = gbuf[262144+idx], g2 = gbuf[524288+idx], g3 = gbuf[786432+idx];
    float cl = cell[idx]*sigm(g0) + sigm(g1)*tanhf(g2);
    hl[r][o] = tanhf(cl)*sigm(g3);
  }
  ylds[r][o][0] = y[idx];
  ylds[r][o][1] = y[262144+idx];
  ylds[r][o][2] = y[524288+idx];
  __syncthreads();
  { // y3 outproj
    float acc = bvec[o];
    const float* hr = hl[r];
    for (int k=0;k<128;++k) acc += hr[k]*W[(size_t)k*128+o];
    ylds[r][o][3] = sigm(acc);
  }
  __syncthreads();
  { // layer 0: 4 -> 3
    const float* w = cwT;
    float a0=0.f, a1=0.f, a2=0.f;
    for (int k=0;k<128;++k){
      float w0 = w[k*256 + o], w1 = w[k*256 + 128 + o];
      float y0 = ylds[r][k][0], y1 = ylds[r][k][1], y2 = ylds[r][k][2], y3 = ylds[r][k][3];
      a0 += y0*w0 + y1*w1; a1 += y1*w0 + y2*w1; a2 += y2*w0 + y3*w1;
    }
    float bb = cb[o];
    __syncthreads();
    ylds[r][o][0] = a0+bb; ylds[r][o][1] = a1+bb; ylds[r][o][2] = a2+bb;
    __syncthreads();
  }
  { // layer 1: 3 -> 2
    const float* w = cwT + 32768;
    float a0=0.f, a1=0.f;
    for (int k=0;k<128;++k){
      float w0 = w[k*256 + o], w1 = w[k*256 + 128 + o];
      float y0 = ylds[r][k][0], y1 = ylds[r][k][1], y2 = ylds[r][k][2];
      a0 += y0*w0 + y1*w1; a1 += y1*w0 + y2*w1;
    }
    float bb = cb[128 + o];
    __syncthreads();
    ylds[r][o][0] = a0+bb; ylds[r][o][1] = a1+bb;
    __syncthreads();
  }
  { // layer 2: 2 -> 1
    const float* w = cwT + 65536;
    float a0=0.f;
    for (int k=0;k<128;++k){
      float w0 = w[k*256 + o], w1 = w[k*256 + 128 + o];
      a0 += ylds[r][k][0]*w0 + ylds[r][k][1]*w1;
    }
    out[idx] = a0 + cb[256 + o];
  }
}

extern "C" void kernel_launch(void* const* d_in, const int* in_sizes, int n_in,
                              void* d_out, int out_size, void* d_ws, size_t ws_size,
                              hipStream_t stream) {
  const float* actors = (const float*)d_in[0];
  const int*   adj    = (const int*)d_in[1];
  const float* Wg     = (const float*)d_in[2];
  const float* ag     = (const float*)d_in[3];
  const float* W      = (const float*)d_in[4];
  const float* b      = (const float*)d_in[5];
  const float* h0     = (const float*)d_in[6];
  const float* cw     = (const float*)d_in[7];
  const float* cb     = (const float*)d_in[8];
  float* out = (float*)d_out;

  char* ws = (char*)d_ws;
  unsigned long long* bm = (unsigned long long*)ws;                  // 2 MB
  float* cell          = (float*)(ws + (size_t)(2u<<20));            // 1 MB
  unsigned short* WgA  = (unsigned short*)(ws + (size_t)(3u<<20));   // 256 KB bf16 swizzled
  float* cwT           = (float*)(ws + (size_t)3407872);             // 384 KB
  float* s_src         = (float*)(ws + (size_t)3932160);             // 32 KB
  float* s_dst         = (float*)(ws + (size_t)3932160 + 32768);     // 32 KB
  unsigned short* WhB  = (unsigned short*)(ws + (size_t)(4u<<20));   // 2 MB bf16 swizzled
  float* gbuf          = (float*)(ws + (size_t)(7u<<20));            // 4 MB [g][n][o]
  float* yplanes       = (float*)(ws + (size_t)(11u<<20));           // 3 MB [t][n][o]

  const int XI[4] = {4, 9, 14, 19};

  prep_kernel<<<3776, 256, 0, stream>>>(actors, Wg, cw, adj, cell, WgA, cwT, bm);
  for (int t=0; t<4; ++t){
    gatewh_kernel<<<128, 256, 0, stream>>>(actors, gbuf, cell, h0, W, b, WgA, ag,
                                           yplanes, WhB, s_src, s_dst, XI[t]*128, t);
    attn_kernel<<<dim3(128,4), 256, 0, stream>>>((const unsigned char*)bm, WhB,
                                                 s_src, s_dst, gbuf, t);
  }
  convgate_kernel<<<1024, 256, 0, stream>>>(gbuf, cell, W, b, yplanes, cwT, cb, out);
}